// Round 1
// baseline (1302.817 us; speedup 1.0000x reference)
//
#include <hip/hip_runtime.h>

#define T_TOK 16384
#define NCODE 8192
#define DIM   256
#define BN    64
#define ITERS (NCODE / BN)   // 128
#define WG_TOKS 64

typedef __attribute__((ext_vector_type(8))) short short8;
typedef __attribute__((ext_vector_type(4))) float floatx4;

__device__ __forceinline__ short f2bf(float x) {
  union { float f; unsigned u; } a; a.f = x;
  unsigned r = a.u + 0x7fffu + ((a.u >> 16) & 1u);   // RNE, no NaN inputs here
  return (short)(r >> 16);
}

// Prep: codebook fp32 -> bf16 copy + per-code squared norms.
// grid 2048 x 256 threads: one wave per code row (256 dims / 64 lanes = float4 each)
__global__ void vq_prep(const float* __restrict__ C, short* __restrict__ cbf,
                        float* __restrict__ cn) {
  int k = blockIdx.x * 4 + (threadIdx.x >> 6);
  int lane = threadIdx.x & 63;
  float4 v = *(const float4*)(C + k * DIM + lane * 4);
  short4 o;
  o.x = f2bf(v.x); o.y = f2bf(v.y); o.z = f2bf(v.z); o.w = f2bf(v.w);
  *(short4*)(cbf + k * DIM + lane * 4) = o;
  float d = v.x * v.x + v.y * v.y + v.z * v.z + v.w * v.w;
  #pragma unroll
  for (int s = 1; s < 64; s <<= 1) d += __shfl_xor(d, s);
  if (lane == 0) cn[k] = d;
}

// Fused flash-style VQ: S = 2 z C^T - ||c||^2 + gumbel -> exp -> (unnormalized)
// P @ C accumulated in registers; normalize by l = sum(exp) at the end.
// Grid: 256 WGs x 256 threads. WG owns 64 tokens; loops 128 chunks of 64 codes.
__global__ __launch_bounds__(256, 1) void vq_main(
    const float* __restrict__ z, const float* __restrict__ u_noise,
    const short* __restrict__ cbf, const float* __restrict__ cn,
    float* __restrict__ out)
{
  // cb rows padded to 264 shorts: 528B stride -> 16B aligned, conflict-free b128 frag reads
  __shared__ short cb[BN][264];        // codebook chunk [code][dim]   33792 B
  __shared__ short pbuf[WG_TOKS][72];  // P chunk [token][code]         9216 B
  __shared__ float lred[2 * WG_TOKS];
  __shared__ float lbuf[WG_TOKS];
  __shared__ float lossred[4];

  const int tid  = threadIdx.x;
  const int wid  = tid >> 6;
  const int lane = tid & 63;
  const int q    = lane >> 4;   // quad
  const int cl   = lane & 15;   // col-in-tile
  const int tokBase  = blockIdx.x * WG_TOKS;
  const int tokHalf  = (wid >> 1) * 32;  // S-phase: which 32 tokens
  const int codeHalf = (wid & 1) * 32;   // S-phase: which 32 codes of the chunk
  const int dimBase  = wid * 64;         // PV-phase: which 64 dims

  // z A-fragments, bf16, resident in registers: A[m=cl][k=q*8+j], 2 Mtiles x 8 ksteps
  short8 za[2][8];
  #pragma unroll
  for (int mt = 0; mt < 2; ++mt) {
    const float* zp = z + (tokBase + tokHalf + mt * 16 + cl) * DIM + q * 8;
    #pragma unroll
    for (int ks = 0; ks < 8; ++ks) {
      float4 f0 = *(const float4*)(zp + ks * 32);
      float4 f1 = *(const float4*)(zp + ks * 32 + 4);
      short8 t;
      t[0] = f2bf(f0.x); t[1] = f2bf(f0.y); t[2] = f2bf(f0.z); t[3] = f2bf(f0.w);
      t[4] = f2bf(f1.x); t[5] = f2bf(f1.y); t[6] = f2bf(f1.z); t[7] = f2bf(f1.w);
      za[mt][ks] = t;
    }
  }

  // O accumulator: 64 tokens x 64 dims per wave (4x4 tiles of 16x16)
  floatx4 Oa[4][4];
  #pragma unroll
  for (int a = 0; a < 4; ++a)
    #pragma unroll
    for (int b = 0; b < 4; ++b)
      Oa[a][b] = (floatx4){0.f, 0.f, 0.f, 0.f};
  float lpart[2][4] = {{0.f, 0.f, 0.f, 0.f}, {0.f, 0.f, 0.f, 0.f}};

  for (int it = 0; it < ITERS; ++it) {
    const int kb = it * BN;

    // ---- stage codebook chunk bf16 into LDS (conflict-free with pad 264) ----
    #pragma unroll
    for (int pass = 0; pass < 8; ++pass) {
      int idx = pass * 256 + tid;           // 2048 chunks of 8 shorts
      int row = idx >> 5, seg = idx & 31;
      short8 v = *(const short8*)(cbf + (kb + row) * DIM + seg * 8);
      *(short8*)&cb[row][seg * 8] = v;
    }

    // ---- prefetch u and code norms (global; overlaps S-phase MFMAs) ----
    float uv[2][2][4];
    float nkv[2];
    #pragma unroll
    for (int nt = 0; nt < 2; ++nt) {
      int codeG = kb + codeHalf + nt * 16 + cl;
      nkv[nt] = cn[codeG];
      #pragma unroll
      for (int mt = 0; mt < 2; ++mt) {
        const float* up = u_noise +
            (tokBase + tokHalf + mt * 16 + q * 4) * NCODE + codeG;
        #pragma unroll
        for (int r = 0; r < 4; ++r) uv[mt][nt][r] = up[r * NCODE];
      }
    }
    __syncthreads();

    // ---- S phase: 32 tok x 32 codes per wave, K=256 ----
    floatx4 acc[2][2];
    #pragma unroll
    for (int a = 0; a < 2; ++a)
      #pragma unroll
      for (int b = 0; b < 2; ++b)
        acc[a][b] = (floatx4){0.f, 0.f, 0.f, 0.f};
    #pragma unroll
    for (int ks = 0; ks < 8; ++ks) {
      short8 b0 = *(const short8*)&cb[codeHalf + cl][ks * 32 + q * 8];
      short8 b1 = *(const short8*)&cb[codeHalf + 16 + cl][ks * 32 + q * 8];
      acc[0][0] = __builtin_amdgcn_mfma_f32_16x16x32_bf16(za[0][ks], b0, acc[0][0], 0, 0, 0);
      acc[0][1] = __builtin_amdgcn_mfma_f32_16x16x32_bf16(za[0][ks], b1, acc[0][1], 0, 0, 0);
      acc[1][0] = __builtin_amdgcn_mfma_f32_16x16x32_bf16(za[1][ks], b0, acc[1][0], 0, 0, 0);
      acc[1][1] = __builtin_amdgcn_mfma_f32_16x16x32_bf16(za[1][ks], b1, acc[1][1], 0, 0, 0);
    }

    // ---- epilogue: p = exp(2 z.c - ||c||^2) / (-log u)   [= exp(logit+g)] ----
    #pragma unroll
    for (int mt = 0; mt < 2; ++mt)
      #pragma unroll
      for (int nt = 0; nt < 2; ++nt)
        #pragma unroll
        for (int r = 0; r < 4; ++r) {
          float sv = acc[mt][nt][r];
          float nl = -__logf(uv[mt][nt][r]);               // in (0, 23.1]
          float p  = __expf(2.f * sv - nkv[nt]) * __builtin_amdgcn_rcpf(nl);
          lpart[mt][r] += p;
          pbuf[tokHalf + mt * 16 + q * 4 + r][codeHalf + nt * 16 + cl] = f2bf(p);
        }
    __syncthreads();

    // ---- PV phase: O(64 tok x 64 dims) += P(64x64) @ C(64 x dims) ----
    #pragma unroll
    for (int ks = 0; ks < 2; ++ks) {
      short8 pa[4];
      #pragma unroll
      for (int mt = 0; mt < 4; ++mt)
        pa[mt] = *(const short8*)&pbuf[mt * 16 + cl][ks * 32 + q * 8];
      #pragma unroll
      for (int nt = 0; nt < 4; ++nt) {
        short8 vb;   // B[k=code=q*8+j][n=dim=cl]: transposed gather from cb
        #pragma unroll
        for (int j = 0; j < 8; ++j)
          vb[j] = cb[ks * 32 + q * 8 + j][dimBase + nt * 16 + cl];
        #pragma unroll
        for (int mt = 0; mt < 4; ++mt)
          Oa[mt][nt] = __builtin_amdgcn_mfma_f32_16x16x32_bf16(pa[mt], vb, Oa[mt][nt], 0, 0, 0);
      }
    }
    __syncthreads();
  }

  // ---- reduce l across the 16 col-lanes of each quad, combine code-halves ----
  #pragma unroll
  for (int mt = 0; mt < 2; ++mt)
    #pragma unroll
    for (int r = 0; r < 4; ++r) {
      float v = lpart[mt][r];
      v += __shfl_xor(v, 1); v += __shfl_xor(v, 2);
      v += __shfl_xor(v, 4); v += __shfl_xor(v, 8);
      if (cl == 0) lred[(wid & 1) * WG_TOKS + tokHalf + mt * 16 + q * 4 + r] = v;
    }
  __syncthreads();
  if (tid < WG_TOKS) lbuf[tid] = lred[tid] + lred[WG_TOKS + tid];
  __syncthreads();

  // ---- normalize, store z_q, accumulate commit loss ----
  float lossAcc = 0.f;
  #pragma unroll
  for (int mt = 0; mt < 4; ++mt)
    #pragma unroll
    for (int nt = 0; nt < 4; ++nt)
      #pragma unroll
      for (int r = 0; r < 4; ++r) {
        int tokL = mt * 16 + q * 4 + r;
        int dimG = dimBase + nt * 16 + cl;
        float val = Oa[mt][nt][r] / lbuf[tokL];
        int off = (tokBase + tokL) * DIM + dimG;
        out[off] = val;
        float dd = val - z[off];
        lossAcc += dd * dd;
      }
  #pragma unroll
  for (int s = 32; s > 0; s >>= 1) lossAcc += __shfl_xor(lossAcc, s);
  if (lane == 0) lossred[wid] = lossAcc;
  __syncthreads();
  if (tid == 0)
    atomicAdd(out + T_TOK * DIM,
              (lossred[0] + lossred[1] + lossred[2] + lossred[3]) *
                  (2.f / (float)(T_TOK * DIM)));
}

extern "C" void kernel_launch(void* const* d_in, const int* in_sizes, int n_in,
                              void* d_out, int out_size, void* d_ws, size_t ws_size,
                              hipStream_t stream) {
  const float* z = (const float*)d_in[0];       // [4,4096,256] fp32
  const float* C = (const float*)d_in[1];       // [8192,256]   fp32
  const float* u = (const float*)d_in[2];       // [16384,8192] fp32
  float* out = (float*)d_out;                   // [16384*256] z_q + [1] loss
  short* cbf = (short*)d_ws;                                    // 4 MB bf16 codebook
  float* cn  = (float*)((char*)d_ws + (size_t)NCODE * DIM * 2); // 32 KB norms

  hipMemsetAsync(out + (size_t)T_TOK * DIM, 0, sizeof(float), stream);
  vq_prep<<<NCODE / 4, 256, 0, stream>>>(C, cbf, cn);
  vq_main<<<T_TOK / WG_TOKS, 256, 0, stream>>>(z, u, cbf, cn, out);
}